// Round 6
// baseline (468.792 us; speedup 1.0000x reference)
//
#include <hip/hip_runtime.h>
#include <hip/hip_bf16.h>
#include <math.h>

#define Hdim 512
#define Bdim 32
#define Sdim 2048
#define Kdim 1024            // 2*H
#define Mtot (Bdim * Sdim)   // 65536 rows

// scores GEMM tiling: block = 64 rows x ALL 512 cols; wave w owns cols [128w,128w+128)
#define BM 64
#define BN 512
#define BK 64                // 8 chunks of 8 bf16 per 128 B LDS row

typedef __attribute__((ext_vector_type(8))) short short8;
typedef __attribute__((ext_vector_type(4))) float floatx4;

// ---------------- fp32 -> bf16 (RNE) ----------------------------------------
__device__ __forceinline__ short f2bf(float f) {
    union { float f; unsigned u; } v; v.f = f;
    unsigned r = v.u + 0x7fffu + ((v.u >> 16) & 1u);
    return (short)(r >> 16);
}

// 8 fp32 -> 8 bf16 via packed converts
__device__ __forceinline__ short8 cvt8(float4 a, float4 b) {
    union { short8 s; __hip_bfloat162 h[4]; } u;
    u.h[0] = __float22bfloat162_rn(make_float2(a.x, a.y));
    u.h[1] = __float22bfloat162_rn(make_float2(a.z, a.w));
    u.h[2] = __float22bfloat162_rn(make_float2(b.x, b.y));
    u.h[3] = __float22bfloat162_rn(make_float2(b.z, b.w));
    return u.s;
}

__device__ __forceinline__ float fast_tanh(float x) {
    float ax = fabsf(x);
    float e  = __expf(-2.0f * ax);
    float r  = (1.0f - e) * __builtin_amdgcn_rcpf(1.0f + e);
    return copysignf(r, x);
}

// ---------------- Kernel 0: prep = conv_W (blocks 0..511) + dec_proj --------
__global__ __launch_bounds__(256) void prep_kernel(
    const float* __restrict__ W_attn, const float* __restrict__ dec,
    const float* __restrict__ b_attn, short* __restrict__ Wb,
    float* __restrict__ dec_proj)
{
    const int t = threadIdx.x;
    if (blockIdx.x < 512) {
        // W_e fp32 [k][n] -> bf16 [n][k] transpose
        const float* We = W_attn + Hdim * Hdim;   // [1024][512]
        __shared__ short tile[32][33];
        const int k0 = (blockIdx.x >> 4) * 32;
        const int n0 = (blockIdx.x & 15) * 32;
        const int r = t >> 5, c = t & 31;
        #pragma unroll
        for (int rr = 0; rr < 4; ++rr)
            tile[r + rr * 8][c] = f2bf(We[(size_t)(k0 + r + rr * 8) * Hdim + n0 + c]);
        __syncthreads();
        #pragma unroll
        for (int rr = 0; rr < 4; ++rr)
            Wb[(size_t)(n0 + r + rr * 8) * Kdim + k0 + c] = tile[c][r + rr * 8];
    } else {
        // dec_proj = decoder_hide @ W_h + b_attn
        __shared__ float partl[2][128];
        const int bid = blockIdx.x - 512;      // 0..127
        const int b  = bid >> 2;
        const int cb = bid & 3;
        const int c  = cb * 128 + (t & 127);
        const int kh = t >> 7;
        float acc = 0.0f;
        const int kbeg = kh * 256, kend = kbeg + 256;
        #pragma unroll 8
        for (int k = kbeg; k < kend; ++k)
            acc = fmaf(dec[b * Hdim + k], W_attn[(size_t)k * Hdim + c], acc);
        partl[kh][t & 127] = acc;
        __syncthreads();
        if (t < 128)
            dec_proj[b * Hdim + cb * 128 + t] = partl[0][t] + partl[1][t] + b_attn[cb * 128 + t];
    }
}

// ---------------- Kernel 1: fused MFMA scores -------------------------------
// A (enc, fp32->bf16) via double-buffered LDS, ONE barrier/iter, reg-prefetch.
// B (Wb, bf16, 1 MB = L2-resident) loaded straight from global into fragments
// each phase -- no LDS, no DMA, nothing for the barrier to drain.
// A LDS rows are 128 B (8 chunks of 16 B); chunk q of row m at p = q ^ (m&7)
// -> conflict-free writes + frag reads (R4/R5-verified).
__global__ __launch_bounds__(256, 2) void scores_kernel(
    const float* __restrict__ enc,      // [65536][1024] fp32
    const short* __restrict__ Wb,       // [512][1024] bf16 (n-major)
    const float* __restrict__ dec_proj, // [32][512]
    const float* __restrict__ v_w,      // [512]
    float* __restrict__ scores)         // [65536]
{
    __shared__ __align__(16) short Asm[2 * BM * BK];   // 16 KB (double-buffered)
    __shared__ float redl[BM][4];                      // 1 KB

    const int t    = threadIdx.x;
    const int row0 = blockIdx.x * BM;
    const int b    = row0 / Sdim;        // 32 m-blocks per batch -> uniform

    const int w    = t >> 6;             // wave 0..3 -> n-slice [128w, 128w+128)
    const int lane = t & 63;
    const int ln   = lane & 15;
    const int quad = lane >> 4;

    // ---- A staging map: thread -> (row sm, quarter sq of 16 fp32) ----
    const int sm = t >> 2;               // 0..63
    const int sq = t & 3;
    const float* Ag = enc + (size_t)(row0 + sm) * Kdim + sq * 16;
    const int awr = sm * BK;
    const int aw0 = ((2 * sq)     ^ (sm & 7)) * 8;
    const int aw1 = ((2 * sq + 1) ^ (sm & 7)) * 8;

    // ---- frag read addresses ----
    int arow[4];
    #pragma unroll
    for (int i = 0; i < 4; ++i) arow[i] = (i * 16 + ln) * BK;
    const int pf0 = (quad       ^ (ln & 7)) * 8;   // k-phase 0 chunks 0..3
    const int pf1 = ((4 + quad) ^ (ln & 7)) * 8;   // k-phase 1 chunks 4..7

    // ---- B per-lane global base: row (w*128 + ln), k-offset quad*8 ----
    const short* Bl = Wb + (size_t)(w * 128 + ln) * Kdim + quad * 8;

    floatx4 acc[4][8];
    #pragma unroll
    for (int i = 0; i < 4; ++i)
        #pragma unroll
        for (int j = 0; j < 8; ++j)
            acc[i][j] = (floatx4)(0.0f);

    // ---- prologue: prefetch A tile 0 into registers ----
    float4 ra0, ra1, ra2, ra3;
    {
        const float4* g = (const float4*)Ag;
        ra0 = g[0]; ra1 = g[1]; ra2 = g[2]; ra3 = g[3];
    }

    for (int kt = 0; kt < Kdim; kt += BK) {
        short* Ab = Asm + ((kt >> 6) & 1) * (BM * BK);
        // ---- stage A (cvt from prefetched regs), swizzled write ----
        *(short8*)&Ab[awr + aw0] = cvt8(ra0, ra1);
        *(short8*)&Ab[awr + aw1] = cvt8(ra2, ra3);
        __syncthreads();   // A writes visible; prior reads of this buf done

        // ---- prefetch next A tile into registers (lands during compute) ----
        if (kt + BK < Kdim) {
            const float4* g = (const float4*)(Ag + kt + BK);
            ra0 = g[0]; ra1 = g[1]; ra2 = g[2]; ra3 = g[3];
        }

        // ---- 2 k-phases x (4 m-tiles x 8 n-tiles) MFMAs, B from global ----
        #pragma unroll
        for (int f = 0; f < 2; ++f) {
            const int pf = f ? pf1 : pf0;
            short8 af[4], bfr[8];
            #pragma unroll
            for (int j = 0; j < 8; ++j)
                bfr[j] = *(const short8*)(Bl + (size_t)j * 16 * Kdim + kt + f * 32);
            #pragma unroll
            for (int i = 0; i < 4; ++i) af[i] = *(const short8*)&Ab[arow[i] + pf];
            #pragma unroll
            for (int i = 0; i < 4; ++i)
                #pragma unroll
                for (int j = 0; j < 8; ++j)
                    acc[i][j] = __builtin_amdgcn_mfma_f32_16x16x32_bf16(
                                    af[i], bfr[j], acc[i][j], 0, 0, 0);
        }
    }

    // ---- epilogue: +dec_proj, tanh, *v_w; each wave sums its 128 cols ----
    float dpv[8], vwv[8];
    #pragma unroll
    for (int j = 0; j < 8; ++j) {
        int col = w * 128 + j * 16 + ln;
        dpv[j] = dec_proj[b * Hdim + col];
        vwv[j] = v_w[col];
    }
    #pragma unroll
    for (int i = 0; i < 4; ++i) {
        #pragma unroll
        for (int reg = 0; reg < 4; ++reg) {
            float s = 0.0f;
            #pragma unroll
            for (int j = 0; j < 8; ++j) {
                float x = acc[i][j][reg] + dpv[j];
                s = fmaf(vwv[j], fast_tanh(x), s);
            }
            s += __shfl_xor(s, 1, 64);
            s += __shfl_xor(s, 2, 64);
            s += __shfl_xor(s, 4, 64);
            s += __shfl_xor(s, 8, 64);
            if (ln == 0)
                redl[i * 16 + quad * 4 + reg][w] = s;
        }
    }
    __syncthreads();
    if (t < BM)
        scores[row0 + t] = redl[t][0] + redl[t][1] + redl[t][2] + redl[t][3];
}

// ---------------- Kernel 2: masked softmax over S per batch -----------------
__global__ __launch_bounds__(256) void softmax_kernel(
    const float* __restrict__ scores, const int* __restrict__ mask,
    float* __restrict__ out)
{
    __shared__ float sred[8];
    const int b = blockIdx.x;
    const int t = threadIdx.x;
    const int lane = t & 63;
    const int wid  = t >> 6;

    float x[8];
    float m = -1e30f;
    #pragma unroll
    for (int j = 0; j < 8; ++j) {
        int idx = b * Sdim + j * 256 + t;
        float v = scores[idx];
        if (mask[idx] == 0) v = -100000.0f;
        x[j] = v;
        m = fmaxf(m, v);
    }
    #pragma unroll
    for (int off = 32; off >= 1; off >>= 1)
        m = fmaxf(m, __shfl_xor(m, off, 64));
    if (lane == 0) sred[wid] = m;
    __syncthreads();
    m = fmaxf(fmaxf(sred[0], sred[1]), fmaxf(sred[2], sred[3]));

    float s = 0.0f;
    #pragma unroll
    for (int j = 0; j < 8; ++j) {
        float e = __expf(x[j] - m);
        x[j] = e;
        s += e;
    }
    #pragma unroll
    for (int off = 32; off >= 1; off >>= 1)
        s += __shfl_xor(s, off, 64);
    if (lane == 0) sred[4 + wid] = s;
    __syncthreads();
    s = sred[4] + sred[5] + sred[6] + sred[7];

    const float inv = 1.0f / s;
    #pragma unroll
    for (int j = 0; j < 8; ++j)
        out[b * Sdim + j * 256 + t] = x[j] * inv;
}

// ---------------- launch ----------------------------------------------------
extern "C" void kernel_launch(void* const* d_in, const int* in_sizes, int n_in,
                              void* d_out, int out_size, void* d_ws, size_t ws_size,
                              hipStream_t stream) {
    const float* dec  = (const float*)d_in[0];   // (B, H)
    const float* enc  = (const float*)d_in[1];   // (B, S, 2H)
    const int*   mask = (const int*)  d_in[2];   // (B, S)
    const float* W    = (const float*)d_in[3];   // (3H, H)
    const float* ba   = (const float*)d_in[4];   // (H,)
    const float* vw   = (const float*)d_in[5];   // (H,)
    float* out = (float*)d_out;                  // (B, S)

    // workspace layout (~1.3 MB)
    float* dec_proj = (float*)d_ws;                       // 32*512 f   = 64 KB
    short* Wb       = (short*)(dec_proj + Bdim * Hdim);   // 512*1024 s = 1 MB
    float* scores   = (float*)(Wb + Hdim * Kdim);         // 65536 f    = 256 KB

    prep_kernel<<<640, 256, 0, stream>>>(W, dec, ba, Wb, dec_proj);
    scores_kernel<<<Mtot / BM, 256, 0, stream>>>(enc, Wb, dec_proj, vw, scores);
    softmax_kernel<<<Bdim, 256, 0, stream>>>(scores, mask, out);
}

// Round 7
// 450.746 us; speedup vs baseline: 1.0400x; 1.0400x over previous
//
#include <hip/hip_runtime.h>
#include <hip/hip_bf16.h>
#include <math.h>

#define Hdim 512
#define Bdim 32
#define Sdim 2048
#define Kdim 1024            // 2*H
#define Mtot (Bdim * Sdim)   // 65536 rows

// scores GEMM tiling: block = 512 thr = 8 waves; block tile 64 rows x 512 cols;
// wave w owns cols [64w, 64w+64) with a 64x64 MFMA tile (acc = 64 VGPR).
#define BM 64
#define BK 64                // 8 chunks of 8 bf16 per 128 B LDS row

typedef __attribute__((ext_vector_type(8))) short short8;
typedef __attribute__((ext_vector_type(4))) float floatx4;

// ---------------- fp32 -> bf16 (RNE) ----------------------------------------
__device__ __forceinline__ short f2bf(float f) {
    union { float f; unsigned u; } v; v.f = f;
    unsigned r = v.u + 0x7fffu + ((v.u >> 16) & 1u);
    return (short)(r >> 16);
}

// 8 fp32 -> 8 bf16 via packed converts
__device__ __forceinline__ short8 cvt8(float4 a, float4 b) {
    union { short8 s; __hip_bfloat162 h[4]; } u;
    u.h[0] = __float22bfloat162_rn(make_float2(a.x, a.y));
    u.h[1] = __float22bfloat162_rn(make_float2(a.z, a.w));
    u.h[2] = __float22bfloat162_rn(make_float2(b.x, b.y));
    u.h[3] = __float22bfloat162_rn(make_float2(b.z, b.w));
    return u.s;
}

__device__ __forceinline__ float fast_tanh(float x) {
    float ax = fabsf(x);
    float e  = __expf(-2.0f * ax);
    float r  = (1.0f - e) * __builtin_amdgcn_rcpf(1.0f + e);
    return copysignf(r, x);
}

// ---------------- Kernel 0: prep = conv_W (blocks 0..511) + dec_proj --------
__global__ __launch_bounds__(256) void prep_kernel(
    const float* __restrict__ W_attn, const float* __restrict__ dec,
    const float* __restrict__ b_attn, short* __restrict__ Wb,
    float* __restrict__ dec_proj)
{
    const int t = threadIdx.x;
    if (blockIdx.x < 512) {
        // W_e fp32 [k][n] -> bf16 [n][k] transpose
        const float* We = W_attn + Hdim * Hdim;   // [1024][512]
        __shared__ short tile[32][33];
        const int k0 = (blockIdx.x >> 4) * 32;
        const int n0 = (blockIdx.x & 15) * 32;
        const int r = t >> 5, c = t & 31;
        #pragma unroll
        for (int rr = 0; rr < 4; ++rr)
            tile[r + rr * 8][c] = f2bf(We[(size_t)(k0 + r + rr * 8) * Hdim + n0 + c]);
        __syncthreads();
        #pragma unroll
        for (int rr = 0; rr < 4; ++rr)
            Wb[(size_t)(n0 + r + rr * 8) * Kdim + k0 + c] = tile[c][r + rr * 8];
    } else {
        // dec_proj = decoder_hide @ W_h + b_attn
        __shared__ float partl[2][128];
        const int bid = blockIdx.x - 512;      // 0..127
        const int b  = bid >> 2;
        const int cb = bid & 3;
        const int c  = cb * 128 + (t & 127);
        const int kh = t >> 7;
        float acc = 0.0f;
        const int kbeg = kh * 256, kend = kbeg + 256;
        #pragma unroll 8
        for (int k = kbeg; k < kend; ++k)
            acc = fmaf(dec[b * Hdim + k], W_attn[(size_t)k * Hdim + c], acc);
        partl[kh][t & 127] = acc;
        __syncthreads();
        if (t < 128)
            dec_proj[b * Hdim + cb * 128 + t] = partl[0][t] + partl[1][t] + b_attn[cb * 128 + t];
    }
}

// ---------------- Kernel 1: fused MFMA scores -------------------------------
// A (enc) fp32->bf16 into double-buffered LDS, ONE drain-free barrier/iter.
// B (Wb bf16, 1 MB, L2-resident) straight global->register each phase.
// ISSUE ORDER per iter: B loads (both phases) FIRST, then A prefetch, so
// vmcnt waits for B never retire the HBM A-load (in-order vmcnt, m135).
// LDS chunk swizzle p = q ^ (row&7): conflict-free (R4/R5-verified 0).
__global__ __launch_bounds__(512, 4) void scores_kernel(
    const float* __restrict__ enc,      // [65536][1024] fp32
    const short* __restrict__ Wb,       // [512][1024] bf16 (n-major)
    const float* __restrict__ dec_proj, // [32][512]
    const float* __restrict__ v_w,      // [512]
    float* __restrict__ scores)         // [65536]
{
    __shared__ __align__(16) short Asm[2 * BM * BK];   // 16 KB double-buffered
    __shared__ float redl[BM][8];                      // 2 KB

    const int t    = threadIdx.x;
    const int row0 = blockIdx.x * BM;
    const int b    = row0 / Sdim;        // uniform per block

    const int w    = t >> 6;             // wave 0..7 -> cols [64w, 64w+64)
    const int lane = t & 63;
    const int ln   = lane & 15;
    const int quad = lane >> 4;

    // ---- A staging: thread -> (row sm, 8-float chunk sq), one short8 write
    const int sm = t >> 3;               // 0..63
    const int sq = t & 7;                // 0..7
    const float* Ag = enc + (size_t)(row0 + sm) * Kdim + sq * 8;
    const int awo = sm * BK + ((sq ^ (sm & 7)) * 8);

    // ---- A frag read addresses ----
    int arow[4];
    #pragma unroll
    for (int i = 0; i < 4; ++i) arow[i] = (i * 16 + ln) * BK;
    const int pf0 = (quad       ^ (ln & 7)) * 8;   // phase 0: chunks 0..3
    const int pf1 = ((4 + quad) ^ (ln & 7)) * 8;   // phase 1: chunks 4..7

    // ---- B per-lane global base: row (w*64 + ln), k-offset quad*8 ----
    const short* Bl = Wb + (size_t)(w * 64 + ln) * Kdim + quad * 8;

    floatx4 acc[4][4];
    #pragma unroll
    for (int i = 0; i < 4; ++i)
        #pragma unroll
        for (int j = 0; j < 4; ++j)
            acc[i][j] = (floatx4)(0.0f);

    // ---- prologue: prefetch A tile 0 (32 B/thread) ----
    float4 ra0, ra1;
    {
        const float4* g = (const float4*)Ag;
        ra0 = g[0]; ra1 = g[1];
    }

    for (int kt = 0; kt < Kdim; kt += BK) {
        short* Ab = Asm + ((kt >> 6) & 1) * (BM * BK);
        // stage A from prefetched regs (waits only on A), swizzled write
        *(short8*)&Ab[awo] = cvt8(ra0, ra1);
        __syncthreads();                 // nothing outstanding -> cheap drain

        // ---- B loads for BOTH phases first (L2 hits, oldest in queue) ----
        short8 b0[4], b1[4];
        #pragma unroll
        for (int j = 0; j < 4; ++j)
            b0[j] = *(const short8*)(Bl + (size_t)j * 16 * Kdim + kt);
        #pragma unroll
        for (int j = 0; j < 4; ++j)
            b1[j] = *(const short8*)(Bl + (size_t)j * 16 * Kdim + kt + 32);

        // ---- A prefetch LAST (HBM; stays in flight through both phases) ----
        if (kt + BK < Kdim) {
            const float4* g = (const float4*)(Ag + kt + BK);
            ra0 = g[0]; ra1 = g[1];
        }

        // ---- phase 0 ----
        short8 af[4];
        #pragma unroll
        for (int i = 0; i < 4; ++i) af[i] = *(const short8*)&Ab[arow[i] + pf0];
        #pragma unroll
        for (int i = 0; i < 4; ++i)
            #pragma unroll
            for (int j = 0; j < 4; ++j)
                acc[i][j] = __builtin_amdgcn_mfma_f32_16x16x32_bf16(
                                af[i], b0[j], acc[i][j], 0, 0, 0);
        // ---- phase 1 ----
        #pragma unroll
        for (int i = 0; i < 4; ++i) af[i] = *(const short8*)&Ab[arow[i] + pf1];
        #pragma unroll
        for (int i = 0; i < 4; ++i)
            #pragma unroll
            for (int j = 0; j < 4; ++j)
                acc[i][j] = __builtin_amdgcn_mfma_f32_16x16x32_bf16(
                                af[i], b1[j], acc[i][j], 0, 0, 0);
    }

    // ---- epilogue: +dec_proj, tanh, *v_w; wave sums its 64 cols ----
    float dpv[4], vwv[4];
    #pragma unroll
    for (int j = 0; j < 4; ++j) {
        int col = w * 64 + j * 16 + ln;
        dpv[j] = dec_proj[b * Hdim + col];
        vwv[j] = v_w[col];
    }
    #pragma unroll
    for (int i = 0; i < 4; ++i) {
        #pragma unroll
        for (int reg = 0; reg < 4; ++reg) {
            float s = 0.0f;
            #pragma unroll
            for (int j = 0; j < 4; ++j) {
                float x = acc[i][j][reg] + dpv[j];
                s = fmaf(vwv[j], fast_tanh(x), s);
            }
            s += __shfl_xor(s, 1, 64);
            s += __shfl_xor(s, 2, 64);
            s += __shfl_xor(s, 4, 64);
            s += __shfl_xor(s, 8, 64);
            if (ln == 0)
                redl[i * 16 + quad * 4 + reg][w] = s;
        }
    }
    __syncthreads();
    if (t < BM) {
        float s = 0.0f;
        #pragma unroll
        for (int wv = 0; wv < 8; ++wv) s += redl[t][wv];
        scores[row0 + t] = s;
    }
}

// ---------------- Kernel 2: masked softmax over S per batch -----------------
__global__ __launch_bounds__(256) void softmax_kernel(
    const float* __restrict__ scores, const int* __restrict__ mask,
    float* __restrict__ out)
{
    __shared__ float sred[8];
    const int b = blockIdx.x;
    const int t = threadIdx.x;
    const int lane = t & 63;
    const int wid  = t >> 6;

    float x[8];
    float m = -1e30f;
    #pragma unroll
    for (int j = 0; j < 8; ++j) {
        int idx = b * Sdim + j * 256 + t;
        float v = scores[idx];
        if (mask[idx] == 0) v = -100000.0f;
        x[j] = v;
        m = fmaxf(m, v);
    }
    #pragma unroll
    for (int off = 32; off >= 1; off >>= 1)
        m = fmaxf(m, __shfl_xor(m, off, 64));
    if (lane == 0) sred[wid] = m;
    __syncthreads();
    m = fmaxf(fmaxf(sred[0], sred[1]), fmaxf(sred[2], sred[3]));

    float s = 0.0f;
    #pragma unroll
    for (int j = 0; j < 8; ++j) {
        float e = __expf(x[j] - m);
        x[j] = e;
        s += e;
    }
    #pragma unroll
    for (int off = 32; off >= 1; off >>= 1)
        s += __shfl_xor(s, off, 64);
    if (lane == 0) sred[4 + wid] = s;
    __syncthreads();
    s = sred[4] + sred[5] + sred[6] + sred[7];

    const float inv = 1.0f / s;
    #pragma unroll
    for (int j = 0; j < 8; ++j)
        out[b * Sdim + j * 256 + t] = x[j] * inv;
}

// ---------------- launch ----------------------------------------------------
extern "C" void kernel_launch(void* const* d_in, const int* in_sizes, int n_in,
                              void* d_out, int out_size, void* d_ws, size_t ws_size,
                              hipStream_t stream) {
    const float* dec  = (const float*)d_in[0];   // (B, H)
    const float* enc  = (const float*)d_in[1];   // (B, S, 2H)
    const int*   mask = (const int*)  d_in[2];   // (B, S)
    const float* W    = (const float*)d_in[3];   // (3H, H)
    const float* ba   = (const float*)d_in[4];   // (H,)
    const float* vw   = (const float*)d_in[5];   // (H,)
    float* out = (float*)d_out;                  // (B, S)

    // workspace layout (~1.3 MB)
    float* dec_proj = (float*)d_ws;                       // 32*512 f   = 64 KB
    short* Wb       = (short*)(dec_proj + Bdim * Hdim);   // 512*1024 s = 1 MB
    float* scores   = (float*)(Wb + Hdim * Kdim);         // 65536 f    = 256 KB

    prep_kernel<<<640, 256, 0, stream>>>(W, dec, ba, Wb, dec_proj);
    scores_kernel<<<Mtot / BM, 512, 0, stream>>>(enc, Wb, dec_proj, vw, scores);
    softmax_kernel<<<Bdim, 256, 0, stream>>>(scores, mask, out);
}